// Round 15
// baseline (86.054 us; speedup 1.0000x reference)
//
#include <hip/hip_runtime.h>

#define NPROTO 512
#define NBLK 8
#define DB 128
#define DM 1024

#define IDX_OFF  8388608
#define VQ_OFF   8454144
#define CL_OFF   8454145

typedef unsigned short u16;
typedef __attribute__((ext_vector_type(8))) _Float16 f16x8;
typedef __attribute__((ext_vector_type(4))) float f32x4;

// ---- ws layout (bytes) ----
#define BH_B   0u
#define BL_B   1048576u
#define CN_B   2097152u
#define PART_B 2113536u
#define WS_NEED (PART_B + 65536u)

// ---- prep: split codes into 2 f16 planes, 16x16x32-operand layout ----
// B16[m][kst][kg][p][8]: flat = (((m*4+kst)*4+kg)*512 + p)*8
// kst = d/32 (K-step), kg = (d%32)/8 (lane k-subgroup)
__global__ __launch_bounds__(256) void vq_prep(const float* __restrict__ src,
                                               u16* __restrict__ hi,
                                               u16* __restrict__ lo,
                                               float* __restrict__ cn) {
    const int t  = threadIdx.x;
    const int p  = blockIdx.x * 32 + (t >> 3);   // global proto 0..4095
    const int g  = t & 7;                        // 16-d slice
    const int m  = p >> 9, pm = p & 511;
    const float* s = src + (size_t)p * DB + g * 16;
    float sq = 0.f;
    ushort4 h[4], l[4];
    #pragma unroll
    for (int j = 0; j < 4; ++j) {
        float4 v = *(const float4*)(s + j * 4);
        float x; _Float16 hf;
        #define S1(c, f) x = v.c; hf = (_Float16)x; h[j].f = __builtin_bit_cast(u16, hf); \
            hf = (_Float16)(x - (float)hf); l[j].f = __builtin_bit_cast(u16, hf); sq += x * x;
        S1(x, x) S1(y, y) S1(z, z) S1(w, w)
        #undef S1
    }
    const int kst = g >> 1, kg0 = (g & 1) * 2;
    const size_t o0 = (((size_t)(m * 4 + kst) * 4 + kg0 + 0) * 512 + pm) * 8;
    const size_t o1 = (((size_t)(m * 4 + kst) * 4 + kg0 + 1) * 512 + pm) * 8;
    *(uint4*)(hi + o0) = *(uint4*)&h[0];
    *(uint4*)(hi + o1) = *(uint4*)&h[2];
    *(uint4*)(lo + o0) = *(uint4*)&l[0];
    *(uint4*)(lo + o1) = *(uint4*)&l[2];
    sq += __shfl_xor(sq, 1, 64);
    sq += __shfl_xor(sq, 2, 64);
    sq += __shfl_xor(sq, 4, 64);
    if ((t & 7) == 0) cn[p] = sq;
}

__device__ __forceinline__ unsigned cvt2(float x, float y, unsigned& lo) {
    _Float16 hx = (_Float16)x, hy = (_Float16)y;
    _Float16 lx = (_Float16)(x - (float)hx), ly = (_Float16)(y - (float)hy);
    lo = (unsigned)__builtin_bit_cast(u16, lx) | ((unsigned)__builtin_bit_cast(u16, ly) << 16);
    return (unsigned)__builtin_bit_cast(u16, hx) | ((unsigned)__builtin_bit_cast(u16, hy) << 16);
}

// ================= fused MFMA main kernel (all-register, LDS-free loop) =====
// r14 post-mortem: 10 µs/CU of ds_read + 68KB LDS capping 8 waves/CU.
// r15: 16x16x32 (r7-proven geometry), 16 rows/wave, A in 32 VGPRs, NO LDS
// in the main loop -> ~108 live regs, tiny LDS -> 16+ waves/CU.
// Accumulation = r13's proven split (aA pure-hh chain + aB lh/hl chain),
// fold = cn - 2*(aA+aB), kst ascending -> indices bit-identical (0.0078).
__global__ __launch_bounds__(256, 2) void vq_fused(
        const float* __restrict__ q, const float* __restrict__ mem,
        const u16* __restrict__ bh, const u16* __restrict__ bl,
        const float* __restrict__ cn, float* __restrict__ out,
        float* __restrict__ partials2) {
    __shared__ float qn_l[64];
    __shared__ int   bp[64];

    const int t    = threadIdx.x;
    const int lane = t & 63;
    const int w    = t >> 6;          // 0..3
    const int pr   = lane & 15;       // proto-in-group / q-row for A
    const int kg   = lane >> 4;       // k-subgroup 0..3
    const int m    = blockIdx.y;
    const int bn0  = blockIdx.x * 64;
    const int rbase = w * 16;

    // ---- A: q row (bn0+rbase+pr), k-slice kg, 4 ksts -> 2 f16 planes ----
    f16x8 ah[4], al[4];
    float qnp = 0.f;
    #pragma unroll
    for (int kst = 0; kst < 4; ++kst) {
        const float* src = q + (size_t)(bn0 + rbase + pr) * DM
                             + m * DB + kst * 32 + kg * 8;
        float4 v0 = ((const float4*)src)[0];
        float4 v1 = ((const float4*)src)[1];
        unsigned l0, l1, l2, l3;
        unsigned h0 = cvt2(v0.x, v0.y, l0), h1 = cvt2(v0.z, v0.w, l1);
        unsigned h2 = cvt2(v1.x, v1.y, l2), h3 = cvt2(v1.z, v1.w, l3);
        uint4 hv = make_uint4(h0, h1, h2, h3), lv = make_uint4(l0, l1, l2, l3);
        ah[kst] = __builtin_bit_cast(f16x8, hv);
        al[kst] = __builtin_bit_cast(f16x8, lv);
        qnp += v0.x*v0.x + v0.y*v0.y + v0.z*v0.z + v0.w*v0.w
             + v1.x*v1.x + v1.y*v1.y + v1.z*v1.z + v1.w*v1.w;
    }
    qnp += __shfl_xor(qnp, 16, 64);
    qnp += __shfl_xor(qnp, 32, 64);
    if (kg == 0) qn_l[rbase + pr] = qnp;

    // ---- main loop: all 512 protos, 16 chunks of 32 (2 groups of 16) ----
    const u16* bh_l = bh + ((size_t)(m * 16 + kg) * 512 + pr) * 8;
    const u16* bl_l = bl + ((size_t)(m * 16 + kg) * 512 + pr) * 8;
    const float* cnb = cn + m * NPROTO + pr;

    float bestv[4]; int besti[4];
    #pragma unroll
    for (int r = 0; r < 4; ++r) { bestv[r] = 3.4e38f; besti[r] = 0; }

    #pragma unroll 2
    for (int c = 0; c < 16; ++c) {
        const float cn0 = cnb[c * 32];
        const float cn1 = cnb[c * 32 + 16];
        const u16* bhc = bh_l + c * 256;
        const u16* blc = bl_l + c * 256;
        f32x4 a0A = {0.f,0.f,0.f,0.f}, a0B = {0.f,0.f,0.f,0.f};
        f32x4 a1A = {0.f,0.f,0.f,0.f}, a1B = {0.f,0.f,0.f,0.f};
        #pragma unroll
        for (int kst = 0; kst < 4; ++kst) {
            f16x8 Bh0 = *(const f16x8*)(bhc + (size_t)kst * 16384);
            f16x8 Bl0 = *(const f16x8*)(blc + (size_t)kst * 16384);
            f16x8 Bh1 = *(const f16x8*)(bhc + (size_t)kst * 16384 + 128);
            f16x8 Bl1 = *(const f16x8*)(blc + (size_t)kst * 16384 + 128);
            a0A = __builtin_amdgcn_mfma_f32_16x16x32_f16(ah[kst], Bh0, a0A, 0, 0, 0);
            a0B = __builtin_amdgcn_mfma_f32_16x16x32_f16(al[kst], Bh0, a0B, 0, 0, 0);
            a0B = __builtin_amdgcn_mfma_f32_16x16x32_f16(ah[kst], Bl0, a0B, 0, 0, 0);
            a1A = __builtin_amdgcn_mfma_f32_16x16x32_f16(ah[kst], Bh1, a1A, 0, 0, 0);
            a1B = __builtin_amdgcn_mfma_f32_16x16x32_f16(al[kst], Bh1, a1B, 0, 0, 0);
            a1B = __builtin_amdgcn_mfma_f32_16x16x32_f16(ah[kst], Bl1, a1B, 0, 0, 0);
        }
        const int ix0 = c * 32 + pr, ix1 = ix0 + 16;
        #pragma unroll
        for (int r = 0; r < 4; ++r) {
            float d0 = cn0 - 2.0f * (a0A[r] + a0B[r]);
            if (d0 < bestv[r]) { bestv[r] = d0; besti[r] = ix0; }
            float d1 = cn1 - 2.0f * (a1A[r] + a1B[r]);
            if (d1 < bestv[r]) { bestv[r] = d1; besti[r] = ix1; }
        }
    }

    // ---- butterfly argmin over the 16 proto-lanes (r7-proven) ----
    #pragma unroll
    for (int r = 0; r < 4; ++r) {
        float v = bestv[r]; int ix = besti[r];
        #pragma unroll
        for (int off = 1; off < 16; off <<= 1) {
            float v2 = __shfl_xor(v, off, 64);
            int  ix2 = __shfl_xor(ix, off, 64);
            if (v2 < v || (v2 == v && ix2 < ix)) { v = v2; ix = ix2; }
        }
        bestv[r] = v; besti[r] = ix;
    }

    // ---- publish (lanes pr==0; rows kg*4+r; wave-private) ----
    if (pr == 0) {
        float lp = 0.f;
        #pragma unroll
        for (int r = 0; r < 4; ++r) {
            int row = rbase + kg * 4 + r;
            bp[row] = besti[r];
            out[(size_t)IDX_OFF + (size_t)(bn0 + row) * NBLK + m] =
                (float)(m * NPROTO + besti[r]);
            lp += bestv[r] + qn_l[row];     // true distance for the loss
        }
        partials2[((size_t)blockIdx.y * gridDim.x + blockIdx.x) * 16 + w * 4 + kg] = lp;
    }

    // ---- gather winning code rows (exact f32 copy; same-wave bp) ----
    {
        const int row = lane >> 2, q4 = lane & 3;
        const int bpi = bp[rbase + row];
        const float* cv = mem + ((size_t)(m * NPROTO + bpi)) * DB + q4 * 32;
        float* ov = out + (size_t)(bn0 + rbase + row) * DM + m * DB + q4 * 32;
        #pragma unroll
        for (int j = 0; j < 8; ++j)
            ((float4*)ov)[j] = ((const float4*)cv)[j];
    }
}

// ================= fallback f32 path (used only if ws too small) =============
__global__ __launch_bounds__(256) void vq_init(const float* __restrict__ mem,
                                               float* __restrict__ cn) {
    int p = blockIdx.x * 256 + threadIdx.x;
    const float* c = mem + (size_t)p * DB;
    float s = 0.f;
    #pragma unroll 8
    for (int k = 0; k < DB; k += 4) {
        float4 v = *(const float4*)(c + k);
        s += v.x * v.x + v.y * v.y + v.z * v.z + v.w * v.w;
    }
    cn[p] = s;
}

__global__ __launch_bounds__(256, 1) void vq_main_f32(const float* __restrict__ q,
                                                      const float* __restrict__ mem,
                                                      const float* __restrict__ cn,
                                                      float* __restrict__ out,
                                                      float* __restrict__ partials) {
    __shared__ float q_lds[128 * 132];
    __shared__ float c_lds[128 * 132];
    __shared__ float red[256];

    const int t    = threadIdx.x;
    const int tile = blockIdx.x;
    const int m    = blockIdx.y;
    const int tr   = t >> 4;
    const int tc   = t & 15;
    const int bn0  = tile * 128;

    const float* qbase = q + (size_t)bn0 * DM + m * DB;
    #pragma unroll
    for (int it = 0; it < 16; ++it) {
        int idx = it * 256 + t;
        int row = idx >> 5;
        int c4  = (idx & 31) << 2;
        *(float4*)&q_lds[row * 132 + c4] = *(const float4*)(qbase + (size_t)row * DM + c4);
    }

    float bestv[8]; int besti[8];
    #pragma unroll
    for (int i = 0; i < 8; ++i) { bestv[i] = 3.4e38f; besti[i] = 0; }
    const float* cbase = mem + (size_t)m * NPROTO * DB;

    for (int ch = 0; ch < 4; ++ch) {
        __syncthreads();
        const float* cb = cbase + (size_t)ch * 128 * DB;
        #pragma unroll
        for (int it = 0; it < 16; ++it) {
            int idx = it * 256 + t;
            int row = idx >> 5;
            int c4  = (idx & 31) << 2;
            *(float4*)&c_lds[row * 132 + c4] = *(const float4*)(cb + row * DB + c4);
        }
        __syncthreads();

        float acc[8][8];
        #pragma unroll
        for (int i = 0; i < 8; ++i)
            #pragma unroll
            for (int j = 0; j < 8; ++j) acc[i][j] = 0.f;

        for (int d4 = 0; d4 < DB; d4 += 4) {
            float4 qa[8], cvv[8];
            #pragma unroll
            for (int i = 0; i < 8; ++i) qa[i] = *(const float4*)&q_lds[(tr + 16 * i) * 132 + d4];
            #pragma unroll
            for (int j = 0; j < 8; ++j) cvv[j] = *(const float4*)&c_lds[(tc + 16 * j) * 132 + d4];
            #pragma unroll
            for (int i = 0; i < 8; ++i)
                #pragma unroll
                for (int j = 0; j < 8; ++j) {
                    acc[i][j] += qa[i].x * cvv[j].x; acc[i][j] += qa[i].y * cvv[j].y;
                    acc[i][j] += qa[i].z * cvv[j].z; acc[i][j] += qa[i].w * cvv[j].w;
                }
        }
        #pragma unroll
        for (int i = 0; i < 8; ++i)
            #pragma unroll
            for (int j = 0; j < 8; ++j) {
                int lp = ch * 128 + tc + 16 * j;
                float dist = cn[m * NPROTO + lp] - 2.0f * acc[i][j];
                if (dist < bestv[i]) { bestv[i] = dist; besti[i] = lp; }
            }
    }

    #pragma unroll
    for (int i = 0; i < 8; ++i) {
        float v = bestv[i]; int ix = besti[i];
        #pragma unroll
        for (int off = 1; off < 16; off <<= 1) {
            float v2 = __shfl_xor(v, off, 64);
            int  ix2 = __shfl_xor(ix, off, 64);
            if (v2 < v || (v2 == v && ix2 < ix)) { v = v2; ix = ix2; }
        }
        bestv[i] = v; besti[i] = ix;
    }

    float lacc = 0.f;
    #pragma unroll
    for (int i = 0; i < 8; ++i) {
        int row = tr + 16 * i;
        int bn  = bn0 + row;
        const float* cvec = cbase + (size_t)besti[i] * DB;
        float* orow = out + (size_t)bn * DM + m * DB;
        #pragma unroll
        for (int h = 0; h < 2; ++h) {
            int colx = h * 64 + tc * 4;
            float4 c4v = *(const float4*)(cvec + colx);
            *(float4*)(orow + colx) = c4v;
            float4 qv2 = *(const float4*)&q_lds[row * 132 + colx];
            float dx = c4v.x - qv2.x, dy = c4v.y - qv2.y;
            float dz = c4v.z - qv2.z, dw = c4v.w - qv2.w;
            lacc += dx * dx + dy * dy + dz * dz + dw * dw;
        }
        if (tc == 0)
            out[(size_t)IDX_OFF + (size_t)bn * NBLK + m] = (float)(m * NPROTO + besti[i]);
    }

    red[t] = lacc;
    __syncthreads();
    for (int s = 128; s > 0; s >>= 1) {
        if (t < s) red[t] += red[t + s];
        __syncthreads();
    }
    if (t == 0) partials[blockIdx.y * gridDim.x + blockIdx.x] = red[0];
}

__global__ __launch_bounds__(256) void vq_final(const float* __restrict__ partials,
                                                float* __restrict__ out, int n) {
    __shared__ float red[256];
    int t = threadIdx.x;
    float v = 0.f;
    for (int i = t; i < n; i += 256) v += partials[i];
    red[t] = v;
    __syncthreads();
    for (int s = 128; s > 0; s >>= 1) {
        if (t < s) red[t] += red[t + s];
        __syncthreads();
    }
    if (t == 0) {
        out[VQ_OFF] = 0.f;
        out[CL_OFF] = red[0] / 8388608.0f;
    }
}

extern "C" void kernel_launch(void* const* d_in, const int* in_sizes, int n_in,
                              void* d_out, int out_size, void* d_ws, size_t ws_size,
                              hipStream_t stream) {
    const float* q   = (const float*)d_in[0];
    const float* mem = (const float*)d_in[1];
    float* out = (float*)d_out;
    char* ws = (char*)d_ws;

    if (ws_size >= (size_t)WS_NEED) {
        u16*   bhp = (u16*)(ws + BH_B);
        u16*   blp = (u16*)(ws + BL_B);
        float* cnp = (float*)(ws + CN_B);
        float* partials = (float*)(ws + PART_B);

        vq_prep<<<128, 256, 0, stream>>>(mem, bhp, blp, cnp);
        dim3 grid(128, 8);
        vq_fused<<<grid, 256, 0, stream>>>(q, mem, bhp, blp, cnp, out, partials);
        vq_final<<<1, 256, 0, stream>>>(partials, out, 16384);
    } else {
        float* cn = (float*)ws;
        float* partials = cn + 4096;
        vq_init<<<16, 256, 0, stream>>>(mem, cn);
        dim3 grid(64, 8);
        vq_main_f32<<<grid, 256, 0, stream>>>(q, mem, cn, out, partials);
        vq_final<<<1, 256, 0, stream>>>(partials, out, 512);
    }
}